// Round 1
// baseline (290.114 us; speedup 1.0000x reference)
//
#include <hip/hip_runtime.h>
#include <hip/hip_bf16.h>
#include <math.h>

#define NB 4
#define NN 8192
#define NC 64
#define NK 16
#define BN_SC 0.9999950000375f  // 1/sqrt(1+1e-5)

typedef __bf16 bf16x8 __attribute__((ext_vector_type(8)));
typedef float  f32x4  __attribute__((ext_vector_type(4)));

struct BlockParams { const float* a[20]; };

__device__ __forceinline__ f32x4 mfma16(bf16x8 a, bf16x8 b, f32x4 c) {
    return __builtin_amdgcn_mfma_f32_16x16x32_bf16(a, b, c, 0, 0, 0);
}

// p (B,3,N) -> pT (B*N, float4{x,y,z,0}) and copy p verbatim to out0
__global__ void prep_p_kernel(const float* __restrict__ p, float4* __restrict__ pT,
                              float* __restrict__ outp) {
    int g = blockIdx.x * 256 + threadIdx.x;      // < NB*NN
    int b = g / NN, n = g % NN;
    float px = p[(b*3+0)*NN + n];
    float py = p[(b*3+1)*NN + n];
    float pz = p[(b*3+2)*NN + n];
    pT[g] = make_float4(px, py, pz, 0.f);
    outp[(b*3+0)*NN + n] = px;
    outp[(b*3+1)*NN + n] = py;
    outp[(b*3+2)*NN + n] = pz;
}

// x (B,C,N) -> xT (B,N,C)
__global__ void transpose_x_kernel(const float* __restrict__ x, float* __restrict__ xT) {
    __shared__ float tile[64][65];
    int b  = blockIdx.x;
    int n0 = blockIdx.y * 64;
    int tl = threadIdx.x & 63;
    int tw = threadIdx.x >> 6;
#pragma unroll
    for (int i = 0; i < 16; ++i) {
        int c = tw*16 + i;
        tile[c][tl] = x[((size_t)b*NC + c)*NN + n0 + tl];
    }
    __syncthreads();
#pragma unroll
    for (int i = 0; i < 16; ++i) {
        int nr = tw*16 + i;
        xT[((size_t)b*NN + n0 + nr)*NC + tl] = tile[tl][nr];
    }
}

// One PT block. Wave = one point at a time (16 neighbors = 16 MFMA rows).
// grid = NB*NN/16 blocks of 256 threads; each block does 16 points (4/wave).
__global__ __launch_bounds__(256, 2) void pt_block_kernel(
    const float4* __restrict__ pT,
    const float*  __restrict__ xin,   // (B,N,C)
    const int*    __restrict__ idx,   // (B,N,K)
    BlockParams P,
    float* __restrict__ out,
    int out_chw)
{
    __shared__ alignas(16) __bf16 sb[4][16*72];   // per-wave stage buffer, pad 72
    __shared__ alignas(16) __bf16 yAll[16*72];    // pooled y for all 16 points

    const float *dw1=P.a[0],  *db1=P.a[1],  *dg1=P.a[2],  *dbe1=P.a[3];
    const float *dw2=P.a[4],  *db2=P.a[5],  *dg2=P.a[6],  *dbe2=P.a[7];
    const float *aw1=P.a[8],  *ab1=P.a[9],  *ag1=P.a[10], *abe1=P.a[11];
    const float *aw2=P.a[12], *ab2=P.a[13], *ag2=P.a[14], *abe2=P.a[15];
    const float *lw =P.a[16], *lb =P.a[17], *lg =P.a[18], *lbe=P.a[19];

    const int tid  = threadIdx.x;
    const int wave = tid >> 6;
    const int lane = tid & 63;
    const int c0   = lane & 15;   // MFMA row (neighbor) / B col
    const int quad = lane >> 4;   // k-group

    const int tile_id = blockIdx.x;
    const int b  = tile_id / (NN/16);
    const int n0 = (tile_id % (NN/16)) * 16;

    // ---- preload per-lane constants (BN scale folded into bf16 weights,
    //      BN bias folded into accumulator init) ----
    // stage1 B-frag: W1 is Cx3; only quad 0, k=0..2 nonzero
    bf16x8 w1bf[4];
    float  b1c[4], b2c[4], b3c[4], b4c[4];
#pragma unroll
    for (int ct = 0; ct < 4; ++ct) {
        int ch = ct*16 + c0;                     // output channel (col)
        float s1 = dg1[ch]*BN_SC;
        float s2 = dg2[ch]*BN_SC;
        float s3 = ag1[ch]*BN_SC;
        float s4 = ag2[ch]*BN_SC;
        b1c[ct] = db1[ch]*s1 + dbe1[ch];
        b2c[ct] = db2[ch]*s2 + dbe2[ch];
        b3c[ct] = ab1[ch]*s3 + abe1[ch];
        b4c[ct] = ab2[ch]*s4 + abe2[ch];
#pragma unroll
        for (int t = 0; t < 8; ++t) w1bf[ct][t] = (__bf16)0.f;
        if (quad == 0) {
            w1bf[ct][0] = (__bf16)(dw1[ch*3+0]*s1);
            w1bf[ct][1] = (__bf16)(dw1[ch*3+1]*s1);
            w1bf[ct][2] = (__bf16)(dw1[ch*3+2]*s1);
        }
    }
    // B-frags for dw2, aw1, aw2 (scale-folded), and down (per-wave col tile)
    bf16x8 w2f[2][4], a1wf[2][4], a2wf[2][4], lwf[2];
#pragma unroll
    for (int s = 0; s < 2; ++s)
#pragma unroll
        for (int ct = 0; ct < 4; ++ct) {
            int row = ct*16 + c0;
            int col = s*32 + quad*8;
            float s2 = dg2[row]*BN_SC, s3 = ag1[row]*BN_SC, s4 = ag2[row]*BN_SC;
#pragma unroll
            for (int t = 0; t < 8; ++t) {
                w2f[s][ct][t]  = (__bf16)(dw2[row*NC + col + t]*s2);
                a1wf[s][ct][t] = (__bf16)(aw1[row*NC + col + t]*s3);
                a2wf[s][ct][t] = (__bf16)(aw2[row*NC + col + t]*s4);
            }
        }
    float lbC;
    {
        int ch = wave*16 + c0;
        float s = lg[ch]*BN_SC;
        lbC = lb[ch]*s + lbe[ch];
#pragma unroll
        for (int sI = 0; sI < 2; ++sI) {
            int col = sI*32 + quad*8;
#pragma unroll
            for (int t = 0; t < 8; ++t) lwf[sI][t] = (__bf16)(lw[ch*NC + col + t]*s);
        }
    }

    __bf16* mysb = sb[wave];

#pragma unroll 1
    for (int pp = 0; pp < 4; ++pp) {
        const int n = n0 + wave*4 + pp;
        const int j = idx[((size_t)b*NN + n)*NK + c0];   // neighbor for row m=c0

        // gather gx row (issued early; used in stage 3)
        const float* xr = &xin[((size_t)b*NN + j)*NC];
        float gx0[8], gx1[8];
        *(float4*)&gx0[0] = *(const float4*)&xr[quad*8];
        *(float4*)&gx0[4] = *(const float4*)&xr[quad*8 + 4];
        *(float4*)&gx1[0] = *(const float4*)&xr[32 + quad*8];
        *(float4*)&gx1[4] = *(const float4*)&xr[32 + quad*8 + 4];

        float4 pj = pT[(size_t)b*NN + j];
        float4 pn = pT[(size_t)b*NN + n];

        // ---- stage 1: rel -> h1 via MFMA (K=3 in a K=32 slot) ----
        bf16x8 afr;
#pragma unroll
        for (int t = 0; t < 8; ++t) afr[t] = (__bf16)0.f;
        if (quad == 0) {
            afr[0] = (__bf16)(pn.x - pj.x);
            afr[1] = (__bf16)(pn.y - pj.y);
            afr[2] = (__bf16)(pn.z - pj.z);
        }
        f32x4 acc[4];
#pragma unroll
        for (int ct = 0; ct < 4; ++ct) {
#pragma unroll
            for (int r = 0; r < 4; ++r) acc[ct][r] = b1c[ct];
            acc[ct] = mfma16(afr, w1bf[ct], acc[ct]);
        }
#pragma unroll
        for (int ct = 0; ct < 4; ++ct)
#pragma unroll
            for (int r = 0; r < 4; ++r)
                mysb[(quad*4+r)*72 + ct*16 + c0] = (__bf16)fmaxf(acc[ct][r], 0.f);

        // ---- stage 2: pe = bn(W2 @ h1 + b2), no relu ----
        {
            bf16x8 h0 = *(const bf16x8*)&mysb[c0*72 + quad*8];
            bf16x8 h1 = *(const bf16x8*)&mysb[c0*72 + 32 + quad*8];
#pragma unroll
            for (int ct = 0; ct < 4; ++ct) {
#pragma unroll
                for (int r = 0; r < 4; ++r) acc[ct][r] = b2c[ct];
                acc[ct] = mfma16(h0, w2f[0][ct], acc[ct]);
                acc[ct] = mfma16(h1, w2f[1][ct], acc[ct]);
            }
#pragma unroll
            for (int ct = 0; ct < 4; ++ct)
#pragma unroll
                for (int r = 0; r < 4; ++r)
                    mysb[(quad*4+r)*72 + ct*16 + c0] = (__bf16)acc[ct][r];
        }

        // ---- stage 3: a1 = relu(bn(A1 @ (gx + pe) + b)) ----
        {
            bf16x8 pe0 = *(const bf16x8*)&mysb[c0*72 + quad*8];
            bf16x8 pe1 = *(const bf16x8*)&mysb[c0*72 + 32 + quad*8];
            bf16x8 tf0, tf1;
#pragma unroll
            for (int t = 0; t < 8; ++t) {
                tf0[t] = (__bf16)(gx0[t] + (float)pe0[t]);
                tf1[t] = (__bf16)(gx1[t] + (float)pe1[t]);
            }
#pragma unroll
            for (int ct = 0; ct < 4; ++ct) {
#pragma unroll
                for (int r = 0; r < 4; ++r) acc[ct][r] = b3c[ct];
                acc[ct] = mfma16(tf0, a1wf[0][ct], acc[ct]);
                acc[ct] = mfma16(tf1, a1wf[1][ct], acc[ct]);
            }
#pragma unroll
            for (int ct = 0; ct < 4; ++ct)
#pragma unroll
                for (int r = 0; r < 4; ++r)
                    mysb[(quad*4+r)*72 + ct*16 + c0] = (__bf16)fmaxf(acc[ct][r], 0.f);
        }

        // ---- stage 4: a2 = relu(bn(A2 @ a1 + b)); max over k; write yAll ----
        {
            bf16x8 a10 = *(const bf16x8*)&mysb[c0*72 + quad*8];
            bf16x8 a11 = *(const bf16x8*)&mysb[c0*72 + 32 + quad*8];
#pragma unroll
            for (int ct = 0; ct < 4; ++ct) {
#pragma unroll
                for (int r = 0; r < 4; ++r) acc[ct][r] = b4c[ct];
                acc[ct] = mfma16(a10, a2wf[0][ct], acc[ct]);
                acc[ct] = mfma16(a11, a2wf[1][ct], acc[ct]);
            }
            float mx0, mx1, mx2, mx3;
#pragma unroll
            for (int ct = 0; ct < 4; ++ct) {
                float m = 0.f;  // relu floor: all candidates >= 0
#pragma unroll
                for (int r = 0; r < 4; ++r) m = fmaxf(m, acc[ct][r]);
                m = fmaxf(m, __shfl_xor(m, 16, 64));
                m = fmaxf(m, __shfl_xor(m, 32, 64));
                if (ct == 0) mx0 = m; else if (ct == 1) mx1 = m;
                else if (ct == 2) mx2 = m; else mx3 = m;
            }
            float mq = (quad == 0) ? mx0 : (quad == 1) ? mx1 : (quad == 2) ? mx2 : mx3;
            yAll[(wave*4+pp)*72 + quad*16 + c0] = (__bf16)mq;
        }
    }

    __syncthreads();

    // ---- down-proj over the 16 points; each wave owns col-tile `wave` ----
    {
        bf16x8 y0 = *(const bf16x8*)&yAll[c0*72 + quad*8];
        bf16x8 y1 = *(const bf16x8*)&yAll[c0*72 + 32 + quad*8];
        f32x4 accd;
#pragma unroll
        for (int r = 0; r < 4; ++r) accd[r] = lbC;
        accd = mfma16(y0, lwf[0], accd);
        accd = mfma16(y1, lwf[1], accd);

        const int ch = wave*16 + c0;
#pragma unroll
        for (int r = 0; r < 4; ++r) {
            int pt_i = quad*4 + r;
            int n = n0 + pt_i;
            float v = accd[r] + xin[((size_t)b*NN + n)*NC + ch];
            if (out_chw) out[((size_t)b*NC + ch)*NN + n] = v;
            else         out[((size_t)b*NN + n)*NC + ch] = v;
        }
    }
}

extern "C" void kernel_launch(void* const* d_in, const int* in_sizes, int n_in,
                              void* d_out, int out_size, void* d_ws, size_t ws_size,
                              hipStream_t stream) {
    (void)in_sizes; (void)n_in; (void)out_size; (void)ws_size;
    const float* p   = (const float*)d_in[0];
    const float* x   = (const float*)d_in[1];
    const int*   idx = (const int*)d_in[2];

    float* pT  = (float*)d_ws;                          // NB*NN*4 floats
    float* xT0 = pT  + (size_t)NB*NN*4;                 // NB*NN*NC
    float* xT1 = xT0 + (size_t)NB*NN*NC;                // NB*NN*NC

    float* out_p = (float*)d_out;                       // (B,3,N)
    float* out_x = out_p + (size_t)NB*3*NN;             // (B,C,N)

    prep_p_kernel<<<(NB*NN)/256, 256, 0, stream>>>(p, (float4*)pT, out_p);
    transpose_x_kernel<<<dim3(NB, NN/64), 256, 0, stream>>>(x, xT0);

    static const int strd[20] = {192,64,64,64, 4096,64,64,64,
                                 4096,64,64,64, 4096,64,64,64,
                                 4096,64,64,64};
    BlockParams P0, P1;
    for (int i = 0; i < 20; ++i) {
        const float* base = (const float*)d_in[3+i];
        P0.a[i] = base;
        P1.a[i] = base + strd[i];
    }

    pt_block_kernel<<<NB*NN/16, 256, 0, stream>>>((const float4*)pT, xT0, idx, P0, xT1, 0);
    pt_block_kernel<<<NB*NN/16, 256, 0, stream>>>((const float4*)pT, xT1, idx, P1, out_x, 1);
}

// Round 2
// 231.199 us; speedup vs baseline: 1.2548x; 1.2548x over previous
//
#include <hip/hip_runtime.h>
#include <hip/hip_bf16.h>
#include <math.h>

#define NB 4
#define NN 8192
#define NC 64
#define NK 16
#define BN_SC 0.9999950000375f  // 1/sqrt(1+1e-5)

typedef __bf16 bf16x8 __attribute__((ext_vector_type(8)));
typedef float  f32x4  __attribute__((ext_vector_type(4)));

struct BlockParams { const float* a[20]; };
struct TwoParams   { BlockParams p[2]; };

// weight buffer layout per param-block (units of bf16x8 = 16B):
//   tiles 0..23 : mats {dw2,aw1,aw2} x (s*4+ct), entry [tile*64+lane]
//   tiles 24..27: w1f (ct), zeros for quad!=0
//   tiles 28..35: lwf (wave*2+s)
// float section at +36*64 units:
//   [0..255]=bias1[c0*4+ct] [256..511]=bias2 [512..767]=bias3 [768..1023]=bias4
//   [1024..1087]=lbC[ch]
#define WTILES 36
#define WBLK_UNITS (WTILES*64 + (1088*4)/16)   // bf16x8 units per block (float sect = 272 units)

__device__ __forceinline__ f32x4 mfma16(bf16x8 a, bf16x8 b, f32x4 c) {
    return __builtin_amdgcn_mfma_f32_16x16x32_bf16(a, b, c, 0, 0, 0);
}

// ---------------- prep kernels ----------------

__global__ void prep_p_kernel(const float* __restrict__ p, float4* __restrict__ pT,
                              float* __restrict__ outp) {
    int g = blockIdx.x * 256 + threadIdx.x;
    int b = g / NN, n = g % NN;
    float px = p[(b*3+0)*NN + n];
    float py = p[(b*3+1)*NN + n];
    float pz = p[(b*3+2)*NN + n];
    pT[g] = make_float4(px, py, pz, 0.f);
    outp[(b*3+0)*NN + n] = px;
    outp[(b*3+1)*NN + n] = py;
    outp[(b*3+2)*NN + n] = pz;
}

__global__ void transpose_x_kernel(const float* __restrict__ x, float* __restrict__ xT) {
    __shared__ float tile[64][65];
    int b  = blockIdx.x;
    int n0 = blockIdx.y * 64;
    int tl = threadIdx.x & 63;
    int tw = threadIdx.x >> 6;
#pragma unroll
    for (int i = 0; i < 16; ++i) {
        int c = tw*16 + i;
        tile[c][tl] = x[((size_t)b*NC + c)*NN + n0 + tl];
    }
    __syncthreads();
#pragma unroll
    for (int i = 0; i < 16; ++i) {
        int nr = tw*16 + i;
        xT[((size_t)b*NN + n0 + nr)*NC + tl] = tile[tl][nr];
    }
}

__global__ void prep_w_kernel(TwoParams PP, bf16x8* __restrict__ wbuf) {
    const BlockParams P = PP.p[blockIdx.x];
    bf16x8* wbo = wbuf + (size_t)blockIdx.x * WBLK_UNITS;
    const int t = threadIdx.x, lane = t & 63, sub = t >> 6;
    const int c0 = lane & 15, q = lane >> 4;

    for (int tile = sub; tile < WTILES; tile += 4) {
        bf16x8 v;
        if (tile < 24) {
            int m = tile >> 3, st = tile & 7, s = st >> 2, ct = st & 3;
            const float* W = P.a[4 + m*4];   // dw2 / aw1 / aw2
            const float* g = P.a[6 + m*4];   // dg2 / ag1 / ag2
            int row = ct*16 + c0; float sc = g[row]*BN_SC;
#pragma unroll
            for (int k = 0; k < 8; ++k) v[k] = (__bf16)(W[row*NC + s*32 + q*8 + k]*sc);
        } else if (tile < 28) {
            int ct = tile - 24; int row = ct*16 + c0;
            float sc = P.a[2][row]*BN_SC;
#pragma unroll
            for (int k = 0; k < 8; ++k) v[k] = (__bf16)0.f;
            if (q == 0) {
                v[0] = (__bf16)(P.a[0][row*3+0]*sc);
                v[1] = (__bf16)(P.a[0][row*3+1]*sc);
                v[2] = (__bf16)(P.a[0][row*3+2]*sc);
            }
        } else {
            int w = (tile-28) >> 1, s = (tile-28) & 1;
            int ch = w*16 + c0; float sc = P.a[18][ch]*BN_SC;
#pragma unroll
            for (int k = 0; k < 8; ++k) v[k] = (__bf16)(P.a[16][ch*NC + s*32 + q*8 + k]*sc);
        }
        wbo[tile*64 + lane] = v;
    }

    float* fbo = (float*)(wbo + WTILES*64);
    {
        int c0b = t >> 2, ct = t & 3, ch = ct*16 + c0b;
        fbo[0*256 + t] = P.a[1][ch]*(P.a[2][ch]*BN_SC)  + P.a[3][ch];
        fbo[1*256 + t] = P.a[5][ch]*(P.a[6][ch]*BN_SC)  + P.a[7][ch];
        fbo[2*256 + t] = P.a[9][ch]*(P.a[10][ch]*BN_SC) + P.a[11][ch];
        fbo[3*256 + t] = P.a[13][ch]*(P.a[14][ch]*BN_SC)+ P.a[15][ch];
        if (t < 64) fbo[1024 + t] = P.a[17][t]*(P.a[18][t]*BN_SC) + P.a[19][t];
    }
}

// ---------------- main PT block ----------------

__global__ __launch_bounds__(256, 2) void pt_block_kernel(
    const float4* __restrict__ pT,
    const float*  __restrict__ xin,   // (B,N,C)
    const int*    __restrict__ idx,
    const bf16x8* __restrict__ wb,    // this block's weight buffer
    float* __restrict__ out,
    int out_chw)
{
    __shared__ alignas(16) __bf16 sb[4][32*72];
    __shared__ alignas(16) __bf16 yAll[16*72];

    const int tid = threadIdx.x, wave = tid >> 6, lane = tid & 63;
    const int c0 = lane & 15, quad = lane >> 4;
    const int b  = blockIdx.x / (NN/16);
    const int n0 = (blockIdx.x % (NN/16)) * 16;

    // ---- early gather issue: idx, p, residual, group-0 gx ----
    int jv[4];
#pragma unroll
    for (int pp = 0; pp < 4; ++pp)
        jv[pp] = idx[((size_t)b*NN + n0 + wave*4 + pp)*NK + c0];
    float4 pnv[4], pjv[4];
#pragma unroll
    for (int pp = 0; pp < 4; ++pp) {
        pnv[pp] = pT[(size_t)b*NN + n0 + wave*4 + pp];
        pjv[pp] = pT[(size_t)b*NN + jv[pp]];
    }
    float resv[4];
#pragma unroll
    for (int r = 0; r < 4; ++r)
        resv[r] = xin[((size_t)b*NN + n0 + quad*4 + r)*NC + wave*16 + c0];

    float gx0f[2][16];
#pragma unroll
    for (int pt = 0; pt < 2; ++pt) {
        const float* xr = &xin[((size_t)b*NN + jv[pt])*NC];
        *(float4*)&gx0f[pt][0]  = *(const float4*)&xr[quad*8];
        *(float4*)&gx0f[pt][4]  = *(const float4*)&xr[quad*8 + 4];
        *(float4*)&gx0f[pt][8]  = *(const float4*)&xr[32 + quad*8];
        *(float4*)&gx0f[pt][12] = *(const float4*)&xr[32 + quad*8 + 4];
    }

    // ---- coalesced weight-fragment loads ----
    bf16x8 w2f[2][4], a1wf[2][4], a2wf[2][4], w1f[4], lwf[2];
#pragma unroll
    for (int s = 0; s < 2; ++s)
#pragma unroll
        for (int ct = 0; ct < 4; ++ct) {
            w2f[s][ct]  = wb[( 0 + s*4+ct)*64 + lane];
            a1wf[s][ct] = wb[( 8 + s*4+ct)*64 + lane];
            a2wf[s][ct] = wb[(16 + s*4+ct)*64 + lane];
        }
#pragma unroll
    for (int ct = 0; ct < 4; ++ct) w1f[ct] = wb[(24+ct)*64 + lane];
#pragma unroll
    for (int s = 0; s < 2; ++s)    lwf[s]  = wb[(28 + wave*2+s)*64 + lane];

    const float* fb = (const float*)(wb + WTILES*64);
    float4 b1v = *(const float4*)&fb[0*256 + c0*4];
    float4 b2v = *(const float4*)&fb[1*256 + c0*4];
    float4 b3v = *(const float4*)&fb[2*256 + c0*4];
    float4 b4v = *(const float4*)&fb[3*256 + c0*4];
    float  lbC = fb[1024 + wave*16 + c0];

    __bf16* mysb = sb[wave];

    auto run_group = [&](int g, float (&gxf)[2][16]) {
        f32x4 acc[2][4];
        // ---- stage 1: rel -> h1 ----
#pragma unroll
        for (int pt = 0; pt < 2; ++pt) {
            int p4 = g*2 + pt;
            bf16x8 afr;
#pragma unroll
            for (int t = 0; t < 8; ++t) afr[t] = (__bf16)0.f;
            if (quad == 0) {
                afr[0] = (__bf16)(pnv[p4].x - pjv[p4].x);
                afr[1] = (__bf16)(pnv[p4].y - pjv[p4].y);
                afr[2] = (__bf16)(pnv[p4].z - pjv[p4].z);
            }
#pragma unroll
            for (int ct = 0; ct < 4; ++ct) {
                f32x4 a;
                float bc = ((const float*)&b1v)[ct];
#pragma unroll
                for (int r = 0; r < 4; ++r) a[r] = bc;
                acc[pt][ct] = mfma16(afr, w1f[ct], a);
            }
        }
#pragma unroll
        for (int pt = 0; pt < 2; ++pt)
#pragma unroll
            for (int ct = 0; ct < 4; ++ct)
#pragma unroll
                for (int r = 0; r < 4; ++r)
                    mysb[(pt*16 + quad*4+r)*72 + ct*16 + c0] = (__bf16)fmaxf(acc[pt][ct][r], 0.f);

        // ---- stage 2: pe = W2 @ h1 + b2 (no relu) ----
        {
            bf16x8 f0[2], f1[2];
#pragma unroll
            for (int pt = 0; pt < 2; ++pt) {
                f0[pt] = *(const bf16x8*)&mysb[(pt*16 + c0)*72 + quad*8];
                f1[pt] = *(const bf16x8*)&mysb[(pt*16 + c0)*72 + 32 + quad*8];
            }
#pragma unroll
            for (int pt = 0; pt < 2; ++pt)
#pragma unroll
                for (int ct = 0; ct < 4; ++ct) {
                    f32x4 a;
                    float bc = ((const float*)&b2v)[ct];
#pragma unroll
                    for (int r = 0; r < 4; ++r) a[r] = bc;
                    a = mfma16(f0[pt], w2f[0][ct], a);
                    acc[pt][ct] = mfma16(f1[pt], w2f[1][ct], a);
                }
#pragma unroll
            for (int pt = 0; pt < 2; ++pt)
#pragma unroll
                for (int ct = 0; ct < 4; ++ct)
#pragma unroll
                    for (int r = 0; r < 4; ++r)
                        mysb[(pt*16 + quad*4+r)*72 + ct*16 + c0] = (__bf16)acc[pt][ct][r];
        }

        // ---- stage 3: a1 = relu(A1 @ (gx + pe) + b3) ----
        {
            bf16x8 t0[2], t1[2];
#pragma unroll
            for (int pt = 0; pt < 2; ++pt) {
                bf16x8 p0 = *(const bf16x8*)&mysb[(pt*16 + c0)*72 + quad*8];
                bf16x8 p1 = *(const bf16x8*)&mysb[(pt*16 + c0)*72 + 32 + quad*8];
#pragma unroll
                for (int t = 0; t < 8; ++t) {
                    t0[pt][t] = (__bf16)(gxf[pt][t]     + (float)p0[t]);
                    t1[pt][t] = (__bf16)(gxf[pt][8 + t] + (float)p1[t]);
                }
            }
#pragma unroll
            for (int pt = 0; pt < 2; ++pt)
#pragma unroll
                for (int ct = 0; ct < 4; ++ct) {
                    f32x4 a;
                    float bc = ((const float*)&b3v)[ct];
#pragma unroll
                    for (int r = 0; r < 4; ++r) a[r] = bc;
                    a = mfma16(t0[pt], a1wf[0][ct], a);
                    acc[pt][ct] = mfma16(t1[pt], a1wf[1][ct], a);
                }
#pragma unroll
            for (int pt = 0; pt < 2; ++pt)
#pragma unroll
                for (int ct = 0; ct < 4; ++ct)
#pragma unroll
                    for (int r = 0; r < 4; ++r)
                        mysb[(pt*16 + quad*4+r)*72 + ct*16 + c0] = (__bf16)fmaxf(acc[pt][ct][r], 0.f);
        }

        // ---- stage 4 + max-pool over k ----
        {
            bf16x8 f0[2], f1[2];
#pragma unroll
            for (int pt = 0; pt < 2; ++pt) {
                f0[pt] = *(const bf16x8*)&mysb[(pt*16 + c0)*72 + quad*8];
                f1[pt] = *(const bf16x8*)&mysb[(pt*16 + c0)*72 + 32 + quad*8];
            }
#pragma unroll
            for (int pt = 0; pt < 2; ++pt) {
#pragma unroll
                for (int ct = 0; ct < 4; ++ct) {
                    f32x4 a;
                    float bc = ((const float*)&b4v)[ct];
#pragma unroll
                    for (int r = 0; r < 4; ++r) a[r] = bc;
                    a = mfma16(f0[pt], a2wf[0][ct], a);
                    acc[pt][ct] = mfma16(f1[pt], a2wf[1][ct], a);
                }
                float mx0, mx1, mx2, mx3;
#pragma unroll
                for (int ct = 0; ct < 4; ++ct) {
                    float m = 0.f;  // relu floor
#pragma unroll
                    for (int r = 0; r < 4; ++r) m = fmaxf(m, acc[pt][ct][r]);
                    m = fmaxf(m, __shfl_xor(m, 16, 64));
                    m = fmaxf(m, __shfl_xor(m, 32, 64));
                    if (ct == 0) mx0 = m; else if (ct == 1) mx1 = m;
                    else if (ct == 2) mx2 = m; else mx3 = m;
                }
                float mq = (quad == 0) ? mx0 : (quad == 1) ? mx1 : (quad == 2) ? mx2 : mx3;
                yAll[(wave*4 + g*2 + pt)*72 + quad*16 + c0] = (__bf16)mq;
            }
        }
    };

    run_group(0, gx0f);

    // group-1 gx loads (compiler may hoist into group-0 compute)
    float gx1f[2][16];
#pragma unroll
    for (int pt = 0; pt < 2; ++pt) {
        const float* xr = &xin[((size_t)b*NN + jv[2+pt])*NC];
        *(float4*)&gx1f[pt][0]  = *(const float4*)&xr[quad*8];
        *(float4*)&gx1f[pt][4]  = *(const float4*)&xr[quad*8 + 4];
        *(float4*)&gx1f[pt][8]  = *(const float4*)&xr[32 + quad*8];
        *(float4*)&gx1f[pt][12] = *(const float4*)&xr[32 + quad*8 + 4];
    }

    run_group(1, gx1f);

    __syncthreads();

    // ---- down-proj (16 points, each wave owns col-tile `wave`) + residual ----
    {
        bf16x8 y0 = *(const bf16x8*)&yAll[c0*72 + quad*8];
        bf16x8 y1 = *(const bf16x8*)&yAll[c0*72 + 32 + quad*8];
        f32x4 accd;
#pragma unroll
        for (int r = 0; r < 4; ++r) accd[r] = lbC;
        accd = mfma16(y0, lwf[0], accd);
        accd = mfma16(y1, lwf[1], accd);

        const int ch = wave*16 + c0;
#pragma unroll
        for (int r = 0; r < 4; ++r) {
            int n = n0 + quad*4 + r;
            float v = accd[r] + resv[r];
            if (out_chw) out[((size_t)b*NC + ch)*NN + n] = v;
            else         out[((size_t)b*NN + n)*NC + ch] = v;
        }
    }
}

extern "C" void kernel_launch(void* const* d_in, const int* in_sizes, int n_in,
                              void* d_out, int out_size, void* d_ws, size_t ws_size,
                              hipStream_t stream) {
    (void)in_sizes; (void)n_in; (void)out_size; (void)ws_size;
    const float* p   = (const float*)d_in[0];
    const float* x   = (const float*)d_in[1];
    const int*   idx = (const int*)d_in[2];

    float* pT  = (float*)d_ws;                          // NB*NN*4 floats
    float* xT0 = pT  + (size_t)NB*NN*4;                 // NB*NN*NC
    float* xT1 = xT0 + (size_t)NB*NN*NC;                // NB*NN*NC
    bf16x8* wbuf = (bf16x8*)(xT1 + (size_t)NB*NN*NC);   // 2 * WBLK_UNITS

    float* out_p = (float*)d_out;                       // (B,3,N)
    float* out_x = out_p + (size_t)NB*3*NN;             // (B,C,N)

    static const int strd[20] = {192,64,64,64, 4096,64,64,64,
                                 4096,64,64,64, 4096,64,64,64,
                                 4096,64,64,64};
    TwoParams PP;
    for (int i = 0; i < 20; ++i) {
        const float* base = (const float*)d_in[3+i];
        PP.p[0].a[i] = base;
        PP.p[1].a[i] = base + strd[i];
    }

    prep_p_kernel<<<(NB*NN)/256, 256, 0, stream>>>(p, (float4*)pT, out_p);
    transpose_x_kernel<<<dim3(NB, NN/64), 256, 0, stream>>>(x, xT0);
    prep_w_kernel<<<2, 256, 0, stream>>>(PP, wbuf);

    pt_block_kernel<<<NB*NN/16, 256, 0, stream>>>((const float4*)pT, xT0, idx,
                                                  wbuf, xT1, 0);
    pt_block_kernel<<<NB*NN/16, 256, 0, stream>>>((const float4*)pT, xT1, idx,
                                                  wbuf + WBLK_UNITS, out_x, 1);
}

// Round 3
// 207.012 us; speedup vs baseline: 1.4014x; 1.1168x over previous
//
#include <hip/hip_runtime.h>
#include <hip/hip_bf16.h>
#include <math.h>

#define NB 4
#define NN 8192
#define NC 64
#define NK 16
#define BN_SC 0.9999950000375f  // 1/sqrt(1+1e-5)

typedef __bf16 bf16x8 __attribute__((ext_vector_type(8)));
typedef float  f32x4  __attribute__((ext_vector_type(4)));

struct BlockParams { const float* a[20]; };
struct TwoParams   { BlockParams p[2]; };

// weight buffer layout per param-block (units of bf16x8 = 16B):
//   tiles 0..23 : mats {dw2,aw1,aw2} x (s*4+ct), entry [tile*64+lane]
//   tiles 24..27: w1f (ct), zeros for quad!=0
//   tiles 28..35: lwf (colt*2+s)
// float section at +36*64 units:
//   [st*256 + c0*4 + ct] = bias_st[ct*16+c0], st=0..3 ; [1024+ch]=lbC
#define WTILES 36
#define WBLK_UNITS (WTILES*64 + (1088*4)/16)

__device__ __forceinline__ f32x4 mfma16(bf16x8 a, bf16x8 b, f32x4 c) {
    return __builtin_amdgcn_mfma_f32_16x16x32_bf16(a, b, c, 0, 0, 0);
}

// ---------------- prep kernels ----------------

__global__ void prep_p_kernel(const float* __restrict__ p, float4* __restrict__ pT,
                              float* __restrict__ outp) {
    int g = blockIdx.x * 256 + threadIdx.x;
    int b = g / NN, n = g % NN;
    float px = p[(b*3+0)*NN + n];
    float py = p[(b*3+1)*NN + n];
    float pz = p[(b*3+2)*NN + n];
    pT[g] = make_float4(px, py, pz, 0.f);
    outp[(b*3+0)*NN + n] = px;
    outp[(b*3+1)*NN + n] = py;
    outp[(b*3+2)*NN + n] = pz;
}

__global__ void transpose_x_kernel(const float* __restrict__ x, float* __restrict__ xT) {
    __shared__ float tile[64][65];
    int b  = blockIdx.x;
    int n0 = blockIdx.y * 64;
    int tl = threadIdx.x & 63;
    int tw = threadIdx.x >> 6;
#pragma unroll
    for (int i = 0; i < 16; ++i) {
        int c = tw*16 + i;
        tile[c][tl] = x[((size_t)b*NC + c)*NN + n0 + tl];
    }
    __syncthreads();
#pragma unroll
    for (int i = 0; i < 16; ++i) {
        int nr = tw*16 + i;
        xT[((size_t)b*NN + n0 + nr)*NC + tl] = tile[tl][nr];
    }
}

__global__ void prep_w_kernel(TwoParams PP, bf16x8* __restrict__ wbuf) {
    const BlockParams P = PP.p[blockIdx.x];
    bf16x8* wbo = wbuf + (size_t)blockIdx.x * WBLK_UNITS;
    const int t = threadIdx.x, lane = t & 63, sub = t >> 6;
    const int c0 = lane & 15, q = lane >> 4;

    for (int tile = sub; tile < WTILES; tile += 4) {
        bf16x8 v;
        if (tile < 24) {
            int m = tile >> 3, st = tile & 7, s = st >> 2, ct = st & 3;
            const float* W = P.a[4 + m*4];   // dw2 / aw1 / aw2
            const float* g = P.a[6 + m*4];   // dg2 / ag1 / ag2
            int row = ct*16 + c0; float sc = g[row]*BN_SC;
#pragma unroll
            for (int k = 0; k < 8; ++k) v[k] = (__bf16)(W[row*NC + s*32 + q*8 + k]*sc);
        } else if (tile < 28) {
            int ct = tile - 24; int row = ct*16 + c0;
            float sc = P.a[2][row]*BN_SC;
#pragma unroll
            for (int k = 0; k < 8; ++k) v[k] = (__bf16)0.f;
            if (q == 0) {
                v[0] = (__bf16)(P.a[0][row*3+0]*sc);
                v[1] = (__bf16)(P.a[0][row*3+1]*sc);
                v[2] = (__bf16)(P.a[0][row*3+2]*sc);
            }
        } else {
            int w = (tile-28) >> 1, s = (tile-28) & 1;
            int ch = w*16 + c0; float sc = P.a[18][ch]*BN_SC;
#pragma unroll
            for (int k = 0; k < 8; ++k) v[k] = (__bf16)(P.a[16][ch*NC + s*32 + q*8 + k]*sc);
        }
        wbo[tile*64 + lane] = v;
    }

    float* fbo = (float*)(wbo + WTILES*64);
    {
        int c0b = t >> 2, ct = t & 3, ch = ct*16 + c0b;
        fbo[0*256 + t] = P.a[1][ch]*(P.a[2][ch]*BN_SC)  + P.a[3][ch];
        fbo[1*256 + t] = P.a[5][ch]*(P.a[6][ch]*BN_SC)  + P.a[7][ch];
        fbo[2*256 + t] = P.a[9][ch]*(P.a[10][ch]*BN_SC) + P.a[11][ch];
        fbo[3*256 + t] = P.a[13][ch]*(P.a[14][ch]*BN_SC)+ P.a[15][ch];
        if (t < 64) fbo[1024 + t] = P.a[17][t]*(P.a[18][t]*BN_SC) + P.a[19][t];
    }
}

// ---------------- main PT block ----------------
// Weights streamed from L2 per stage (ct-halves) => no spills, 4 waves/SIMD.

__global__ __launch_bounds__(256, 4) void pt_block_kernel(
    const float4* __restrict__ pT,
    const float*  __restrict__ xin,   // (B,N,C)
    const int*    __restrict__ idx,
    const bf16x8* __restrict__ wb,
    float* __restrict__ out,
    int out_chw)
{
    __shared__ alignas(16) __bf16 sb[4][32*72];
    __shared__ alignas(16) __bf16 yAll[16*72];

    const int tid = threadIdx.x, wave = tid >> 6, lane = tid & 63;
    const int c0 = lane & 15, quad = lane >> 4;

    // XCD-aware swizzle: blockIdx%8 -> XCD; batch b pinned to XCD pair
    const int x  = blockIdx.x;
    const int b  = x & 3;
    const int n0 = ((((x >> 2) & 1) << 8) | (x >> 3)) * 16;

    const float*  xb = xin + (size_t)b * NN * NC;
    const float4* pb = pT  + (size_t)b * NN;
    const float*  fb = (const float*)(wb + WTILES*64);

    int jv[4];
#pragma unroll
    for (int pp = 0; pp < 4; ++pp)
        jv[pp] = idx[((size_t)b*NN + n0 + wave*4 + pp)*NK + c0];

    __bf16 relb[4][3];
#pragma unroll
    for (int pp = 0; pp < 4; ++pp) {
        float4 pn = pb[n0 + wave*4 + pp];
        float4 pj = pb[jv[pp]];
        relb[pp][0] = (__bf16)(pn.x - pj.x);
        relb[pp][1] = (__bf16)(pn.y - pj.y);
        relb[pp][2] = (__bf16)(pn.z - pj.z);
    }

    __bf16* mysb = sb[wave];

    auto load_gx = [&](int j, bf16x8& ga, bf16x8& gb) {
        const float* xr = &xb[(size_t)j * NC];
        float4 q0 = *(const float4*)&xr[quad*8];
        float4 q1 = *(const float4*)&xr[quad*8 + 4];
        float4 q2 = *(const float4*)&xr[32 + quad*8];
        float4 q3 = *(const float4*)&xr[32 + quad*8 + 4];
        ga[0]=(__bf16)q0.x; ga[1]=(__bf16)q0.y; ga[2]=(__bf16)q0.z; ga[3]=(__bf16)q0.w;
        ga[4]=(__bf16)q1.x; ga[5]=(__bf16)q1.y; ga[6]=(__bf16)q1.z; ga[7]=(__bf16)q1.w;
        gb[0]=(__bf16)q2.x; gb[1]=(__bf16)q2.y; gb[2]=(__bf16)q2.z; gb[3]=(__bf16)q2.w;
        gb[4]=(__bf16)q3.x; gb[5]=(__bf16)q3.y; gb[6]=(__bf16)q3.z; gb[7]=(__bf16)q3.w;
    };

    auto run_group = [&](int g, bf16x8 (&gx)[2][2]) {
        // ---- stage 1: rel -> h1 (K=3 in K=32 slot) ----
        {
            bf16x8 afr[2];
#pragma unroll
            for (int pt = 0; pt < 2; ++pt) {
#pragma unroll
                for (int t = 0; t < 8; ++t) afr[pt][t] = (__bf16)0.f;
                if (quad == 0) {
                    afr[pt][0] = relb[g*2+pt][0];
                    afr[pt][1] = relb[g*2+pt][1];
                    afr[pt][2] = relb[g*2+pt][2];
                }
            }
            float4 bv = *(const float4*)&fb[0*256 + c0*4];
#pragma unroll
            for (int h = 0; h < 2; ++h) {
                bf16x8 wf[2];
                wf[0] = wb[(24 + h*2 + 0)*64 + lane];
                wf[1] = wb[(24 + h*2 + 1)*64 + lane];
#pragma unroll
                for (int pt = 0; pt < 2; ++pt)
#pragma unroll
                    for (int cc = 0; cc < 2; ++cc) {
                        int ct = h*2 + cc;
                        f32x4 a;
                        float bc = ((const float*)&bv)[ct];
#pragma unroll
                        for (int r = 0; r < 4; ++r) a[r] = bc;
                        a = mfma16(afr[pt], wf[cc], a);
#pragma unroll
                        for (int r = 0; r < 4; ++r)
                            mysb[(pt*16 + quad*4 + r)*72 + ct*16 + c0] = (__bf16)fmaxf(a[r], 0.f);
                    }
            }
        }
        // ---- stage 2: pe = W2 @ h1 + b2 ----
        {
            bf16x8 f0[2], f1[2];
#pragma unroll
            for (int pt = 0; pt < 2; ++pt) {
                f0[pt] = *(const bf16x8*)&mysb[(pt*16 + c0)*72 + quad*8];
                f1[pt] = *(const bf16x8*)&mysb[(pt*16 + c0)*72 + 32 + quad*8];
            }
            float4 bv = *(const float4*)&fb[1*256 + c0*4];
#pragma unroll
            for (int h = 0; h < 2; ++h) {
                bf16x8 w0[2], w1[2];
#pragma unroll
                for (int cc = 0; cc < 2; ++cc) {
                    w0[cc] = wb[(0 + h*2 + cc)*64 + lane];
                    w1[cc] = wb[(4 + h*2 + cc)*64 + lane];
                }
#pragma unroll
                for (int pt = 0; pt < 2; ++pt)
#pragma unroll
                    for (int cc = 0; cc < 2; ++cc) {
                        int ct = h*2 + cc;
                        f32x4 a;
                        float bc = ((const float*)&bv)[ct];
#pragma unroll
                        for (int r = 0; r < 4; ++r) a[r] = bc;
                        a = mfma16(f0[pt], w0[cc], a);
                        a = mfma16(f1[pt], w1[cc], a);
#pragma unroll
                        for (int r = 0; r < 4; ++r)
                            mysb[(pt*16 + quad*4 + r)*72 + ct*16 + c0] = (__bf16)a[r];
                    }
            }
        }
        // ---- stage 3: a1 = relu(A1 @ (gx + pe) + b3) ----
        {
            bf16x8 t0[2], t1[2];
#pragma unroll
            for (int pt = 0; pt < 2; ++pt) {
                bf16x8 p0 = *(const bf16x8*)&mysb[(pt*16 + c0)*72 + quad*8];
                bf16x8 p1 = *(const bf16x8*)&mysb[(pt*16 + c0)*72 + 32 + quad*8];
#pragma unroll
                for (int t = 0; t < 8; ++t) {
                    t0[pt][t] = (__bf16)((float)gx[pt][0][t] + (float)p0[t]);
                    t1[pt][t] = (__bf16)((float)gx[pt][1][t] + (float)p1[t]);
                }
            }
            float4 bv = *(const float4*)&fb[2*256 + c0*4];
#pragma unroll
            for (int h = 0; h < 2; ++h) {
                bf16x8 w0[2], w1[2];
#pragma unroll
                for (int cc = 0; cc < 2; ++cc) {
                    w0[cc] = wb[( 8 + h*2 + cc)*64 + lane];
                    w1[cc] = wb[(12 + h*2 + cc)*64 + lane];
                }
#pragma unroll
                for (int pt = 0; pt < 2; ++pt)
#pragma unroll
                    for (int cc = 0; cc < 2; ++cc) {
                        int ct = h*2 + cc;
                        f32x4 a;
                        float bc = ((const float*)&bv)[ct];
#pragma unroll
                        for (int r = 0; r < 4; ++r) a[r] = bc;
                        a = mfma16(t0[pt], w0[cc], a);
                        a = mfma16(t1[pt], w1[cc], a);
#pragma unroll
                        for (int r = 0; r < 4; ++r)
                            mysb[(pt*16 + quad*4 + r)*72 + ct*16 + c0] = (__bf16)fmaxf(a[r], 0.f);
                    }
            }
        }
        // ---- stage 4 + max-pool over k ----
        {
            bf16x8 f0[2], f1[2];
#pragma unroll
            for (int pt = 0; pt < 2; ++pt) {
                f0[pt] = *(const bf16x8*)&mysb[(pt*16 + c0)*72 + quad*8];
                f1[pt] = *(const bf16x8*)&mysb[(pt*16 + c0)*72 + 32 + quad*8];
            }
            float4 bv = *(const float4*)&fb[3*256 + c0*4];
            float mx[2][4];
#pragma unroll
            for (int h = 0; h < 2; ++h) {
                bf16x8 w0[2], w1[2];
#pragma unroll
                for (int cc = 0; cc < 2; ++cc) {
                    w0[cc] = wb[(16 + h*2 + cc)*64 + lane];
                    w1[cc] = wb[(20 + h*2 + cc)*64 + lane];
                }
#pragma unroll
                for (int pt = 0; pt < 2; ++pt)
#pragma unroll
                    for (int cc = 0; cc < 2; ++cc) {
                        int ct = h*2 + cc;
                        f32x4 a;
                        float bc = ((const float*)&bv)[ct];
#pragma unroll
                        for (int r = 0; r < 4; ++r) a[r] = bc;
                        a = mfma16(f0[pt], w0[cc], a);
                        a = mfma16(f1[pt], w1[cc], a);
                        float m = 0.f;  // relu floor
#pragma unroll
                        for (int r = 0; r < 4; ++r) m = fmaxf(m, a[r]);
                        mx[pt][ct] = m;
                    }
            }
#pragma unroll
            for (int pt = 0; pt < 2; ++pt) {
                float m0 = mx[pt][0], m1 = mx[pt][1], m2 = mx[pt][2], m3 = mx[pt][3];
                m0 = fmaxf(m0, __shfl_xor(m0, 16, 64));
                m0 = fmaxf(m0, __shfl_xor(m0, 32, 64));
                m1 = fmaxf(m1, __shfl_xor(m1, 16, 64));
                m1 = fmaxf(m1, __shfl_xor(m1, 32, 64));
                m2 = fmaxf(m2, __shfl_xor(m2, 16, 64));
                m2 = fmaxf(m2, __shfl_xor(m2, 32, 64));
                m3 = fmaxf(m3, __shfl_xor(m3, 16, 64));
                m3 = fmaxf(m3, __shfl_xor(m3, 32, 64));
                float mq = (quad == 0) ? m0 : (quad == 1) ? m1 : (quad == 2) ? m2 : m3;
                yAll[(wave*4 + g*2 + pt)*72 + quad*16 + c0] = (__bf16)mq;
            }
        }
    };

    bf16x8 gx0[2][2];
    load_gx(jv[0], gx0[0][0], gx0[0][1]);
    load_gx(jv[1], gx0[1][0], gx0[1][1]);
    run_group(0, gx0);

    bf16x8 gx1[2][2];
    load_gx(jv[2], gx1[0][0], gx1[0][1]);
    load_gx(jv[3], gx1[1][0], gx1[1][1]);
    // block CSE/hoist of group-1 weight loads into group 0 (register blowup)
    asm volatile("" ::: "memory");
    run_group(1, gx1);

    __syncthreads();

    // ---- down-proj over 16 points + residual ----
    {
        bf16x8 y0  = *(const bf16x8*)&yAll[c0*72 + quad*8];
        bf16x8 y1  = *(const bf16x8*)&yAll[c0*72 + 32 + quad*8];
        bf16x8 lw0 = wb[(28 + wave*2 + 0)*64 + lane];
        bf16x8 lw1 = wb[(28 + wave*2 + 1)*64 + lane];
        float  lbC = fb[1024 + wave*16 + c0];
        f32x4 a;
#pragma unroll
        for (int r = 0; r < 4; ++r) a[r] = lbC;
        a = mfma16(y0, lw0, a);
        a = mfma16(y1, lw1, a);

        const int ch = wave*16 + c0;
#pragma unroll
        for (int r = 0; r < 4; ++r) {
            int n = n0 + quad*4 + r;
            float v = a[r] + xb[(size_t)n*NC + ch];
            if (out_chw) out[((size_t)b*NC + ch)*NN + n] = v;
            else         out[((size_t)b*NN + n)*NC + ch] = v;
        }
    }
}

extern "C" void kernel_launch(void* const* d_in, const int* in_sizes, int n_in,
                              void* d_out, int out_size, void* d_ws, size_t ws_size,
                              hipStream_t stream) {
    (void)in_sizes; (void)n_in; (void)out_size; (void)ws_size;
    const float* p   = (const float*)d_in[0];
    const float* x   = (const float*)d_in[1];
    const int*   idx = (const int*)d_in[2];

    float* pT  = (float*)d_ws;                          // NB*NN*4 floats
    float* xT0 = pT  + (size_t)NB*NN*4;                 // NB*NN*NC
    float* xT1 = xT0 + (size_t)NB*NN*NC;                // NB*NN*NC
    bf16x8* wbuf = (bf16x8*)(xT1 + (size_t)NB*NN*NC);   // 2 * WBLK_UNITS

    float* out_p = (float*)d_out;                       // (B,3,N)
    float* out_x = out_p + (size_t)NB*3*NN;             // (B,C,N)

    static const int strd[20] = {192,64,64,64, 4096,64,64,64,
                                 4096,64,64,64, 4096,64,64,64,
                                 4096,64,64,64};
    TwoParams PP;
    for (int i = 0; i < 20; ++i) {
        const float* base = (const float*)d_in[3+i];
        PP.p[0].a[i] = base;
        PP.p[1].a[i] = base + strd[i];
    }

    prep_p_kernel<<<(NB*NN)/256, 256, 0, stream>>>(p, (float4*)pT, out_p);
    transpose_x_kernel<<<dim3(NB, NN/64), 256, 0, stream>>>(x, xT0);
    prep_w_kernel<<<2, 256, 0, stream>>>(PP, wbuf);

    pt_block_kernel<<<NB*NN/16, 256, 0, stream>>>((const float4*)pT, xT0, idx,
                                                  wbuf, xT1, 0);
    pt_block_kernel<<<NB*NN/16, 256, 0, stream>>>((const float4*)pT, xT1, idx,
                                                  wbuf + WBLK_UNITS, out_x, 1);
}

// Round 4
// 205.789 us; speedup vs baseline: 1.4098x; 1.0059x over previous
//
#include <hip/hip_runtime.h>
#include <hip/hip_bf16.h>
#include <math.h>

#define NB 4
#define NN 8192
#define NC 64
#define NK 16
#define BN_SC 0.9999950000375f  // 1/sqrt(1+1e-5)

typedef __bf16 bf16x8 __attribute__((ext_vector_type(8)));
typedef __bf16 bf16x4 __attribute__((ext_vector_type(4)));
typedef float  f32x4  __attribute__((ext_vector_type(4)));

struct BlockParams { const float* a[20]; };
struct TwoParams   { BlockParams p[2]; };

// weight buffer layout per param-block (units of bf16x8 = 16B):
//   tiles 0..23 : mats {dw2,aw1,aw2} x (s*4+ct), entry [tile*64+lane]
//   tiles 24..27: w1f (ct), zeros for quad!=0
//   tiles 28..35: lwf (colt*2+s)
// float section at +36*64 units: fb[st*64+ch] st=0..3 stage biases; fb[256+ch]=lbC
#define WTILES 36
#define WBLK_UNITS (WTILES*64 + (320*4)/16)

__device__ __forceinline__ f32x4 mfma16(bf16x8 a, bf16x8 b, f32x4 c) {
    return __builtin_amdgcn_mfma_f32_16x16x32_bf16(a, b, c, 0, 0, 0);
}

// ---------------- prep kernels ----------------

__global__ void prep_p_kernel(const float* __restrict__ p, float4* __restrict__ pT,
                              float* __restrict__ outp) {
    int g = blockIdx.x * 256 + threadIdx.x;
    int b = g / NN, n = g % NN;
    float px = p[(b*3+0)*NN + n];
    float py = p[(b*3+1)*NN + n];
    float pz = p[(b*3+2)*NN + n];
    pT[g] = make_float4(px, py, pz, 0.f);
    outp[(b*3+0)*NN + n] = px;
    outp[(b*3+1)*NN + n] = py;
    outp[(b*3+2)*NN + n] = pz;
}

__global__ void transpose_x_kernel(const float* __restrict__ x, float* __restrict__ xT) {
    __shared__ float tile[64][65];
    int b  = blockIdx.x;
    int n0 = blockIdx.y * 64;
    int tl = threadIdx.x & 63;
    int tw = threadIdx.x >> 6;
#pragma unroll
    for (int i = 0; i < 16; ++i) {
        int c = tw*16 + i;
        tile[c][tl] = x[((size_t)b*NC + c)*NN + n0 + tl];
    }
    __syncthreads();
#pragma unroll
    for (int i = 0; i < 16; ++i) {
        int nr = tw*16 + i;
        xT[((size_t)b*NN + n0 + nr)*NC + tl] = tile[tl][nr];
    }
}

__global__ void prep_w_kernel(TwoParams PP, bf16x8* __restrict__ wbuf) {
    const BlockParams P = PP.p[blockIdx.x];
    bf16x8* wbo = wbuf + (size_t)blockIdx.x * WBLK_UNITS;
    const int t = threadIdx.x, lane = t & 63, sub = t >> 6;
    const int c0 = lane & 15, q = lane >> 4;

    for (int tile = sub; tile < WTILES; tile += 4) {
        bf16x8 v;
        if (tile < 24) {
            int m = tile >> 3, st = tile & 7, s = st >> 2, ct = st & 3;
            const float* W = P.a[4 + m*4];   // dw2 / aw1 / aw2
            const float* g = P.a[6 + m*4];   // dg2 / ag1 / ag2
            int row = ct*16 + c0; float sc = g[row]*BN_SC;
#pragma unroll
            for (int k = 0; k < 8; ++k) v[k] = (__bf16)(W[row*NC + s*32 + q*8 + k]*sc);
        } else if (tile < 28) {
            int ct = tile - 24; int row = ct*16 + c0;
            float sc = P.a[2][row]*BN_SC;
#pragma unroll
            for (int k = 0; k < 8; ++k) v[k] = (__bf16)0.f;
            if (q == 0) {
                v[0] = (__bf16)(P.a[0][row*3+0]*sc);
                v[1] = (__bf16)(P.a[0][row*3+1]*sc);
                v[2] = (__bf16)(P.a[0][row*3+2]*sc);
            }
        } else {
            int w = (tile-28) >> 1, s = (tile-28) & 1;
            int ch = w*16 + c0; float sc = P.a[18][ch]*BN_SC;
#pragma unroll
            for (int k = 0; k < 8; ++k) v[k] = (__bf16)(P.a[16][ch*NC + s*32 + q*8 + k]*sc);
        }
        wbo[tile*64 + lane] = v;
    }

    float* fbo = (float*)(wbo + WTILES*64);
    if (t < 64) {
        int ch = t;
        fbo[0*64 + ch] = P.a[1][ch]*(P.a[2][ch]*BN_SC)  + P.a[3][ch];
        fbo[1*64 + ch] = P.a[5][ch]*(P.a[6][ch]*BN_SC)  + P.a[7][ch];
        fbo[2*64 + ch] = P.a[9][ch]*(P.a[10][ch]*BN_SC) + P.a[11][ch];
        fbo[3*64 + ch] = P.a[13][ch]*(P.a[14][ch]*BN_SC)+ P.a[15][ch];
        fbo[4*64 + ch] = P.a[17][ch]*(P.a[18][ch]*BN_SC)+ P.a[19][ch];
    }
}

// ---------------- main PT block ----------------
// Stages 1-3 run MFMA with A=weights, B=activations => D is [ch][nb]:
// each lane's 4 acc values are 4 consecutive channels -> one ds_write_b64.
// Stage 4 runs A=activations, B=weights so the k-max is a register+shfl max.
// gx folded into stage-2 acc init; residual folded into down-proj acc init.

__global__ __launch_bounds__(256, 4) void pt_block_kernel(
    const float4* __restrict__ pT,
    const float*  __restrict__ xin,   // (B,N,C)
    const int*    __restrict__ idx,
    const bf16x8* __restrict__ wb,
    float* __restrict__ out,
    int out_chw)
{
    __shared__ alignas(16) __bf16 sb[4][2][16*72];  // per wave, per pt-in-group
    __shared__ alignas(16) __bf16 yAll[16*72];

    const int tid = threadIdx.x, wave = tid >> 6, lane = tid & 63;
    const int c0 = lane & 15, quad = lane >> 4;

    const int x  = blockIdx.x;
    const int b  = x & 3;
    const int n0 = ((((x >> 2) & 1) << 8) | (x >> 3)) * 16;

    const float*  xb = xin + (size_t)b * NN * NC;
    const float4* pb = pT  + (size_t)b * NN;
    const float*  fb = (const float*)(wb + WTILES*64);

    int jv[4];
#pragma unroll
    for (int pp = 0; pp < 4; ++pp)
        jv[pp] = idx[((size_t)b*NN + n0 + wave*4 + pp)*NK + c0];

    __bf16 relb[4][3];
#pragma unroll
    for (int pp = 0; pp < 4; ++pp) {
        float4 pn = pb[n0 + wave*4 + pp];
        float4 pj = pb[jv[pp]];
        relb[pp][0] = (__bf16)(pn.x - pj.x);
        relb[pp][1] = (__bf16)(pn.y - pj.y);
        relb[pp][2] = (__bf16)(pn.z - pj.z);
    }

    // gx in D-layout: lane (c0,quad) reads chs ct*16+quad*4.. of row jv[pt]
    auto load_gxD = [&](int j, float4 (&g)[4]) {
        const float* xr = &xb[(size_t)j * NC];
#pragma unroll
        for (int ct = 0; ct < 4; ++ct)
            g[ct] = *(const float4*)&xr[ct*16 + quad*4];
    };

    float4 gx0[2][4];
    load_gxD(jv[0], gx0[0]);
    load_gxD(jv[1], gx0[1]);

    auto run_group = [&](int g, float4 (&gxD)[2][4]) {
        __bf16* buf0 = sb[wave][0];
        __bf16* buf1 = sb[wave][1];

        // ---- stage 1 (swapped): h1 = relu(W1 @ rel + b1), D=[ch][nb] ----
        {
            bf16x8 afr[2];
#pragma unroll
            for (int pt = 0; pt < 2; ++pt) {
#pragma unroll
                for (int t = 0; t < 8; ++t) afr[pt][t] = (__bf16)0.f;
                if (quad == 0) {
                    afr[pt][0] = relb[g*2+pt][0];
                    afr[pt][1] = relb[g*2+pt][1];
                    afr[pt][2] = relb[g*2+pt][2];
                }
            }
#pragma unroll
            for (int ct = 0; ct < 4; ++ct) {
                bf16x8 w = wb[(24+ct)*64 + lane];
                float4 bv = *(const float4*)&fb[0*64 + ct*16 + quad*4];
#pragma unroll
                for (int pt = 0; pt < 2; ++pt) {
                    f32x4 a;
#pragma unroll
                    for (int r = 0; r < 4; ++r) a[r] = ((const float*)&bv)[r];
                    a = mfma16(w, afr[pt], a);
                    bf16x4 pk;
#pragma unroll
                    for (int r = 0; r < 4; ++r) pk[r] = (__bf16)fmaxf(a[r], 0.f);
                    *(bf16x4*)&(pt ? buf1 : buf0)[c0*72 + ct*16 + quad*4] = pk;
                }
            }
        }
        // ---- stage 2 (swapped): t = W2 @ h1 + b2 + gx  (gx in acc init) ----
        {
            bf16x8 f0[2], f1[2];
            f0[0] = *(const bf16x8*)&buf0[c0*72 + quad*8];
            f1[0] = *(const bf16x8*)&buf0[c0*72 + 32 + quad*8];
            f0[1] = *(const bf16x8*)&buf1[c0*72 + quad*8];
            f1[1] = *(const bf16x8*)&buf1[c0*72 + 32 + quad*8];
#pragma unroll
            for (int ct = 0; ct < 4; ++ct) {
                bf16x8 w0 = wb[(0+ct)*64 + lane];
                bf16x8 w1 = wb[(4+ct)*64 + lane];
                float4 bv = *(const float4*)&fb[1*64 + ct*16 + quad*4];
#pragma unroll
                for (int pt = 0; pt < 2; ++pt) {
                    f32x4 a;
#pragma unroll
                    for (int r = 0; r < 4; ++r)
                        a[r] = ((const float*)&bv)[r] + ((const float*)&gxD[pt][ct])[r];
                    a = mfma16(w0, f0[pt], a);
                    a = mfma16(w1, f1[pt], a);
                    bf16x4 pk;
#pragma unroll
                    for (int r = 0; r < 4; ++r) pk[r] = (__bf16)a[r];
                    *(bf16x4*)&(pt ? buf1 : buf0)[c0*72 + ct*16 + quad*4] = pk;
                }
            }
        }
        // ---- stage 3 (swapped): a1 = relu(A1 @ t + b3) ----
        {
            bf16x8 f0[2], f1[2];
            f0[0] = *(const bf16x8*)&buf0[c0*72 + quad*8];
            f1[0] = *(const bf16x8*)&buf0[c0*72 + 32 + quad*8];
            f0[1] = *(const bf16x8*)&buf1[c0*72 + quad*8];
            f1[1] = *(const bf16x8*)&buf1[c0*72 + 32 + quad*8];
#pragma unroll
            for (int ct = 0; ct < 4; ++ct) {
                bf16x8 w0 = wb[( 8+ct)*64 + lane];
                bf16x8 w1 = wb[(12+ct)*64 + lane];
                float4 bv = *(const float4*)&fb[2*64 + ct*16 + quad*4];
#pragma unroll
                for (int pt = 0; pt < 2; ++pt) {
                    f32x4 a;
#pragma unroll
                    for (int r = 0; r < 4; ++r) a[r] = ((const float*)&bv)[r];
                    a = mfma16(w0, f0[pt], a);
                    a = mfma16(w1, f1[pt], a);
                    bf16x4 pk;
#pragma unroll
                    for (int r = 0; r < 4; ++r) pk[r] = (__bf16)fmaxf(a[r], 0.f);
                    *(bf16x4*)&(pt ? buf1 : buf0)[c0*72 + ct*16 + quad*4] = pk;
                }
            }
        }
        // ---- stage 4 (normal): a2 = relu(A2 @ a1 + b4); max over nb ----
        {
            bf16x8 f0[2], f1[2];
            f0[0] = *(const bf16x8*)&buf0[c0*72 + quad*8];
            f1[0] = *(const bf16x8*)&buf0[c0*72 + 32 + quad*8];
            f0[1] = *(const bf16x8*)&buf1[c0*72 + quad*8];
            f1[1] = *(const bf16x8*)&buf1[c0*72 + 32 + quad*8];
            float mx[2][4];
#pragma unroll
            for (int ct = 0; ct < 4; ++ct) {
                bf16x8 w0 = wb[(16+ct)*64 + lane];
                bf16x8 w1 = wb[(20+ct)*64 + lane];
                float bc = fb[3*64 + ct*16 + c0];
#pragma unroll
                for (int pt = 0; pt < 2; ++pt) {
                    f32x4 a;
#pragma unroll
                    for (int r = 0; r < 4; ++r) a[r] = bc;
                    a = mfma16(f0[pt], w0, a);
                    a = mfma16(f1[pt], w1, a);
                    float m = 0.f;  // relu floor
#pragma unroll
                    for (int r = 0; r < 4; ++r) m = fmaxf(m, a[r]);
                    mx[pt][ct] = m;
                }
            }
#pragma unroll
            for (int pt = 0; pt < 2; ++pt) {
                float m0 = mx[pt][0], m1 = mx[pt][1], m2 = mx[pt][2], m3 = mx[pt][3];
                m0 = fmaxf(m0, __shfl_xor(m0, 16, 64));
                m0 = fmaxf(m0, __shfl_xor(m0, 32, 64));
                m1 = fmaxf(m1, __shfl_xor(m1, 16, 64));
                m1 = fmaxf(m1, __shfl_xor(m1, 32, 64));
                m2 = fmaxf(m2, __shfl_xor(m2, 16, 64));
                m2 = fmaxf(m2, __shfl_xor(m2, 32, 64));
                m3 = fmaxf(m3, __shfl_xor(m3, 16, 64));
                m3 = fmaxf(m3, __shfl_xor(m3, 32, 64));
                float mq = (quad == 0) ? m0 : (quad == 1) ? m1 : (quad == 2) ? m2 : m3;
                yAll[(wave*4 + g*2 + pt)*72 + quad*16 + c0] = (__bf16)mq;
            }
        }
    };

    run_group(0, gx0);

    float4 gx1[2][4];
    load_gxD(jv[2], gx1[0]);
    load_gxD(jv[3], gx1[1]);
    asm volatile("" ::: "memory");   // block weight-load hoisting across groups
    run_group(1, gx1);

    __syncthreads();

    // ---- down-proj (swapped): D=[ch][pt]; residual in acc init ----
    {
        bf16x8 y0  = *(const bf16x8*)&yAll[c0*72 + quad*8];
        bf16x8 y1  = *(const bf16x8*)&yAll[c0*72 + 32 + quad*8];
        bf16x8 lw0 = wb[(28 + wave*2 + 0)*64 + lane];
        bf16x8 lw1 = wb[(28 + wave*2 + 1)*64 + lane];
        float4 lb4 = *(const float4*)&fb[4*64 + wave*16 + quad*4];
        float4 res = *(const float4*)&xb[(size_t)(n0 + c0)*NC + wave*16 + quad*4];
        f32x4 a;
#pragma unroll
        for (int r = 0; r < 4; ++r)
            a[r] = ((const float*)&lb4)[r] + ((const float*)&res)[r];
        a = mfma16(lw0, y0, a);
        a = mfma16(lw1, y1, a);

        if (out_chw) {
#pragma unroll
            for (int r = 0; r < 4; ++r)
                out[((size_t)b*NC + wave*16 + quad*4 + r)*NN + n0 + c0] = a[r];
        } else {
            float4 v = make_float4(a[0], a[1], a[2], a[3]);
            *(float4*)&out[((size_t)b*NN + n0 + c0)*NC + wave*16 + quad*4] = v;
        }
    }
}

extern "C" void kernel_launch(void* const* d_in, const int* in_sizes, int n_in,
                              void* d_out, int out_size, void* d_ws, size_t ws_size,
                              hipStream_t stream) {
    (void)in_sizes; (void)n_in; (void)out_size; (void)ws_size;
    const float* p   = (const float*)d_in[0];
    const float* x   = (const float*)d_in[1];
    const int*   idx = (const int*)d_in[2];

    float* pT  = (float*)d_ws;                          // NB*NN*4 floats
    float* xT0 = pT  + (size_t)NB*NN*4;                 // NB*NN*NC
    float* xT1 = xT0 + (size_t)NB*NN*NC;                // NB*NN*NC
    bf16x8* wbuf = (bf16x8*)(xT1 + (size_t)NB*NN*NC);   // 2 * WBLK_UNITS

    float* out_p = (float*)d_out;                       // (B,3,N)
    float* out_x = out_p + (size_t)NB*3*NN;             // (B,C,N)

    static const int strd[20] = {192,64,64,64, 4096,64,64,64,
                                 4096,64,64,64, 4096,64,64,64,
                                 4096,64,64,64};
    TwoParams PP;
    for (int i = 0; i < 20; ++i) {
        const float* base = (const float*)d_in[3+i];
        PP.p[0].a[i] = base;
        PP.p[1].a[i] = base + strd[i];
    }

    prep_p_kernel<<<(NB*NN)/256, 256, 0, stream>>>(p, (float4*)pT, out_p);
    transpose_x_kernel<<<dim3(NB, NN/64), 256, 0, stream>>>(x, xT0);
    prep_w_kernel<<<2, 256, 0, stream>>>(PP, wbuf);

    pt_block_kernel<<<NB*NN/16, 256, 0, stream>>>((const float4*)pT, xT0, idx,
                                                  wbuf, xT1, 0);
    pt_block_kernel<<<NB*NN/16, 256, 0, stream>>>((const float4*)pT, xT1, idx,
                                                  wbuf + WBLK_UNITS, out_x, 1);
}